// Round 4
// baseline (751.907 us; speedup 1.0000x reference)
//
#include <hip/hip_runtime.h>

#define WDIM 160
#define CH 12
#define BLK 256

// binning: CELL=8 (power of 2), 20 cells/dim, 8000 buckets (padded to 8192)
#define NB 20
#define NBUCKETS (NB*NB*NB)      // 8000
#define NBPAD 8192

typedef float v4f __attribute__((ext_vector_type(4)));

__device__ __forceinline__ void fma4(v4f& a, float w, const v4f& v) {
    a.x = fmaf(w, v.x, a.x);
    a.y = fmaf(w, v.y, a.y);
    a.z = fmaf(w, v.z, a.z);
    a.w = fmaf(w, v.w, a.w);
}

__device__ __forceinline__ void point_prep(const float* xyz, int i,
                                           float& px, float& py, float& pz, int& bucket) {
    px = fminf(fmaxf(xyz[3*i+0] * 159.0f, 0.0f), 159.0f);
    py = fminf(fmaxf(xyz[3*i+1] * 159.0f, 0.0f), 159.0f);
    pz = fminf(fmaxf(xyz[3*i+2] * 159.0f, 0.0f), 159.0f);
    int x0 = (int)px, y0 = (int)py, z0 = (int)pz;   // >=0: trunc == floor
    bucket = ((x0 >> 3) * NB + (y0 >> 3)) * NB + (z0 >> 3);
}

__device__ __forceinline__ void trilerp_core(const float* __restrict__ grid,
                                             float px, float py, float pz,
                                             v4f& a0, v4f& a1, v4f& a2) {
    const int x0 = (int)px, y0 = (int)py, z0 = (int)pz;
    const float fx = px - (float)x0, fy = py - (float)y0, fz = pz - (float)z0;
    const float gx = 1.0f - fx, gy = 1.0f - fy, gz = 1.0f - fz;
    const int x1 = min(x0 + 1, WDIM - 1), y1 = min(y0 + 1, WDIM - 1), z1 = min(z0 + 1, WDIM - 1);
    const float w000 = gx*gy*gz, w001 = gx*gy*fz, w010 = gx*fy*gz, w011 = gx*fy*fz;
    const float w100 = fx*gy*gz, w101 = fx*gy*fz, w110 = fx*fy*gz, w111 = fx*fy*fz;
    const int b00 = ((x0*WDIM + y0)*WDIM)*CH, b01 = ((x0*WDIM + y1)*WDIM)*CH;
    const int b10 = ((x1*WDIM + y0)*WDIM)*CH, b11 = ((x1*WDIM + y1)*WDIM)*CH;
    const int oz0 = z0*CH, oz1 = z1*CH;
    a0 = (v4f)(0.0f); a1 = (v4f)(0.0f); a2 = (v4f)(0.0f);
    const v4f* c;
    c = reinterpret_cast<const v4f*>(grid + b00 + oz0); fma4(a0,w000,c[0]); fma4(a1,w000,c[1]); fma4(a2,w000,c[2]);
    c = reinterpret_cast<const v4f*>(grid + b00 + oz1); fma4(a0,w001,c[0]); fma4(a1,w001,c[1]); fma4(a2,w001,c[2]);
    c = reinterpret_cast<const v4f*>(grid + b01 + oz0); fma4(a0,w010,c[0]); fma4(a1,w010,c[1]); fma4(a2,w010,c[2]);
    c = reinterpret_cast<const v4f*>(grid + b01 + oz1); fma4(a0,w011,c[0]); fma4(a1,w011,c[1]); fma4(a2,w011,c[2]);
    c = reinterpret_cast<const v4f*>(grid + b10 + oz0); fma4(a0,w100,c[0]); fma4(a1,w100,c[1]); fma4(a2,w100,c[2]);
    c = reinterpret_cast<const v4f*>(grid + b10 + oz1); fma4(a0,w101,c[0]); fma4(a1,w101,c[1]); fma4(a2,w101,c[2]);
    c = reinterpret_cast<const v4f*>(grid + b11 + oz0); fma4(a0,w110,c[0]); fma4(a1,w110,c[1]); fma4(a2,w110,c[2]);
    c = reinterpret_cast<const v4f*>(grid + b11 + oz1); fma4(a0,w111,c[0]); fma4(a1,w111,c[1]); fma4(a2,w111,c[2]);
}

// ---- K1: histogram via direct global atomics (8000 hot L2 lines) ----
__global__ __launch_bounds__(BLK) void hist_kernel(const float* __restrict__ xyz,
                                                   unsigned* __restrict__ hist, int n) {
    const int stride = gridDim.x * BLK;
    for (int i = blockIdx.x * BLK + threadIdx.x; i < n; i += stride) {
        float px, py, pz; int b;
        point_prep(xyz, i, px, py, pz, b);
        atomicAdd(&hist[b], 1u);
    }
}

// ---- K2: exclusive scan of 8192 counts (single block) ----
__global__ __launch_bounds__(BLK) void scan_kernel(const unsigned* __restrict__ hist,
                                                   unsigned* __restrict__ starts,
                                                   unsigned* __restrict__ cursor) {
    __shared__ unsigned part[BLK];
    __shared__ unsigned base[BLK];
    const int t = threadIdx.x;
    unsigned h[32];
    unsigned s = 0;
    for (int j = 0; j < 32; j++) { h[j] = hist[t*32 + j]; s += h[j]; }
    part[t] = s;
    __syncthreads();
    if (t == 0) {
        unsigned run = 0;
        for (int k = 0; k < BLK; k++) { base[k] = run; run += part[k]; }
    }
    __syncthreads();
    unsigned run = base[t];
    for (int j = 0; j < 32; j++) {
        starts[t*32 + j] = run;
        cursor[t*32 + j] = run;
        run += h[j];
    }
}

// ---- K3: scatter records into bucket order ----
__global__ __launch_bounds__(BLK) void scatter_kernel(const float* __restrict__ xyz,
                                                      unsigned* __restrict__ cursor,
                                                      v4f* __restrict__ recs, int n) {
    const int stride = gridDim.x * BLK;
    for (int i = blockIdx.x * BLK + threadIdx.x; i < n; i += stride) {
        float px, py, pz; int b;
        point_prep(xyz, i, px, py, pz, b);
        unsigned pos = atomicAdd(&cursor[b], 1u);
        v4f r; r.x = px; r.y = py; r.z = pz; r.w = __uint_as_float((unsigned)i);
        __builtin_nontemporal_store(r, &recs[pos]);
    }
}

// ---- K4: gather, direct from global (L1/L2-hot via sort), no LDS ----
__global__ __launch_bounds__(BLK) void gather_direct(const v4f* __restrict__ recs,
                                                     const float* __restrict__ grid,
                                                     float* __restrict__ out,
                                                     int n, int chunks_per_xcd) {
    // XCD-contiguous swizzle: presumed xcd = blockIdx%8 gets a contiguous
    // span of sorted records -> contiguous region of space -> L2 locality.
    const unsigned g = blockIdx.x;
    const unsigned chunk = (g & 7u) * (unsigned)chunks_per_xcd + (g >> 3);
    const int i = (int)(chunk * BLK + threadIdx.x);
    if (i >= n) return;

    v4f r = __builtin_nontemporal_load(&recs[i]);
    const unsigned idx = __float_as_uint(r.w);

    v4f a0, a1, a2;
    trilerp_core(grid, r.x, r.y, r.z, a0, a1, a2);

    v4f* o = reinterpret_cast<v4f*>(out + (size_t)idx * CH);
    __builtin_nontemporal_store(a0, o + 0);
    __builtin_nontemporal_store(a1, o + 1);
    __builtin_nontemporal_store(a2, o + 2);
}

// ---- fallback: direct kernel if ws too small ----
__global__ __launch_bounds__(BLK) void trilerp_direct(const float* __restrict__ xyz,
                                                      const float* __restrict__ grid,
                                                      float* __restrict__ out, int n) {
    const int i = blockIdx.x * BLK + threadIdx.x;
    if (i >= n) return;
    float px, py, pz; int b;
    point_prep(xyz, i, px, py, pz, b);
    v4f a0, a1, a2;
    trilerp_core(grid, px, py, pz, a0, a1, a2);
    v4f* o = reinterpret_cast<v4f*>(out + (size_t)i * CH);
    __builtin_nontemporal_store(a0, o + 0);
    __builtin_nontemporal_store(a1, o + 1);
    __builtin_nontemporal_store(a2, o + 2);
}

extern "C" void kernel_launch(void* const* d_in, const int* in_sizes, int n_in,
                              void* d_out, int out_size, void* d_ws, size_t ws_size,
                              hipStream_t stream) {
    const float* xyz  = (const float*)d_in[0];
    const float* grid = (const float*)d_in[1];
    float* out = (float*)d_out;
    const int n = in_sizes[0] / 3;   // 2,000,000 points

    const size_t recs_bytes = (size_t)n * 16;
    const size_t hist_off   = recs_bytes;
    const size_t starts_off = hist_off + NBPAD * 4;
    const size_t cursor_off = starts_off + NBPAD * 4;
    const size_t ws_needed  = cursor_off + NBPAD * 4;

    if (ws_size < ws_needed) {
        trilerp_direct<<<(n + BLK - 1) / BLK, BLK, 0, stream>>>(xyz, grid, out, n);
        return;
    }

    char* ws = (char*)d_ws;
    v4f*      recs   = (v4f*)ws;
    unsigned* hist   = (unsigned*)(ws + hist_off);
    unsigned* starts = (unsigned*)(ws + starts_off);
    unsigned* cursor = (unsigned*)(ws + cursor_off);

    hipMemsetAsync(hist, 0, NBPAD * 4, stream);
    hist_kernel<<<2048, BLK, 0, stream>>>(xyz, hist, n);
    scan_kernel<<<1, BLK, 0, stream>>>(hist, starts, cursor);
    scatter_kernel<<<2048, BLK, 0, stream>>>(xyz, cursor, recs, n);

    int nchunks = (n + BLK - 1) / BLK;               // 7813
    int chunks_per_xcd = (nchunks + 7) / 8;          // 977
    int nblocks = chunks_per_xcd * 8;                // 7816
    gather_direct<<<nblocks, BLK, 0, stream>>>(recs, grid, out, n, chunks_per_xcd);
}